// Round 2
// baseline (236.579 us; speedup 1.0000x reference)
//
#include <hip/hip_runtime.h>

#define ROW_T   8192
#define THREADS 1024
#define ITEMS   8                    // elems per thread (2 x float4)
#define NWAVES  (THREADS / 64)       // 16
#define EPSV    1e-4f

typedef float fvec4 __attribute__((ext_vector_type(4)));  // clang vector: NT-store OK

__global__ __launch_bounds__(THREADS, 8)   // 8 waves/SIMD -> 2 blocks/CU, VGPR<=64
void cumnorm_kernel(const float* __restrict__ x, float* __restrict__ out) {
    __shared__ float wbs[NWAVES];
    __shared__ float wbss[NWAVES];

    const int t    = threadIdx.x;
    const int lane = t & 63;
    const int wid  = t >> 6;

    const float* __restrict__ xr   = x   + (long long)blockIdx.x * ROW_T;
    float* __restrict__       outr = out + (long long)blockIdx.x * ROW_T;

    const int e0 = t * ITEMS;

    // Two back-to-back float4 loads; lane stride 32B -> adjacent lanes share a
    // 64B line, requests coalesce 2:1. Whole row loaded in one shot.
    const fvec4 va = *reinterpret_cast<const fvec4*>(xr + e0);
    const fvec4 vb = *reinterpret_cast<const fvec4*>(xr + e0 + 4);

    // ---- thread-local (s, ss) over 8 consecutive elems (pairwise for deps) ----
    float s  = ((va.x + va.y) + (va.z + va.w)) + ((vb.x + vb.y) + (vb.z + vb.w));
    float ss = fmaf(va.x, va.x, fmaf(va.y, va.y, fmaf(va.z, va.z, va.w * va.w)));
    ss = fmaf(vb.x, vb.x, fmaf(vb.y, vb.y, fmaf(vb.z, vb.z, fmaf(vb.w, vb.w, ss))));

    // ---- wave-wide inclusive scan of (s, ss): the ONLY scan for the row ----
    float is = s, iss = ss;
    #pragma unroll
    for (int off = 1; off < 64; off <<= 1) {
        const float us  = __shfl_up(is, off);
        const float uss = __shfl_up(iss, off);
        if (lane >= off) { is += us; iss += uss; }
    }
    if (lane == 63) { wbs[wid] = is; wbss[wid] = iss; }
    __syncthreads();                           // single barrier per row

    // ---- cross-wave exclusive combine (broadcast reads, no conflicts) ----
    float cs = 0.f, css = 0.f;
    #pragma unroll
    for (int w = 0; w < NWAVES; ++w) {
        const float a = wbs[w], b = wbss[w];
        if (w < wid) { cs += a; css += b; }
    }

    // exclusive prefix at this thread's first element
    float S  = cs  + (is  - s);
    float SS = css + (iss - ss);

    // ---- serial finish over own 8 elems, normalize ----
    fvec4 o0, o1;
#define CN_STEP(v, idx, dst) {                                            \
        S += (v); SS = fmaf((v), (v), SS);                                \
        const float inv  = __builtin_amdgcn_rcpf((float)(e0 + (idx) + 1));\
        const float mean = S * inv;                                       \
        const float var  = fmaf(SS, inv, -(mean * mean));                 \
        (dst) = ((v) - mean) * __builtin_amdgcn_rsqf(var + EPSV);         \
    }
    CN_STEP(va.x, 0, o0.x)
    CN_STEP(va.y, 1, o0.y)
    CN_STEP(va.z, 2, o0.z)
    CN_STEP(va.w, 3, o0.w)
    CN_STEP(vb.x, 4, o1.x)
    CN_STEP(vb.y, 5, o1.y)
    CN_STEP(vb.z, 6, o1.z)
    CN_STEP(vb.w, 7, o1.w)
#undef CN_STEP

    // Nontemporal stores: output is never re-read; keep input resident in L3.
    __builtin_nontemporal_store(o0, reinterpret_cast<fvec4*>(outr + e0));
    __builtin_nontemporal_store(o1, reinterpret_cast<fvec4*>(outr + e0 + 4));
}

extern "C" void kernel_launch(void* const* d_in, const int* in_sizes, int n_in,
                              void* d_out, int out_size, void* d_ws, size_t ws_size,
                              hipStream_t stream) {
    const float* x = (const float*)d_in[0];
    float* out = (float*)d_out;
    const int rows = out_size / ROW_T;   // 4096
    cumnorm_kernel<<<rows, THREADS, 0, stream>>>(x, out);
}